// Round 1
// baseline (850.174 us; speedup 1.0000x reference)
//
#include <hip/hip_runtime.h>

typedef unsigned short ushort;
typedef unsigned int   uint;
typedef short bf16x8 __attribute__((ext_vector_type(8)));
typedef float f32x4  __attribute__((ext_vector_type(4)));

// ---------- helpers ----------
__device__ __forceinline__ float bf2f(ushort u){
  union { uint u; float f; } c; c.u = ((uint)u) << 16; return c.f;
}
__device__ __forceinline__ ushort f2bf(float f){
  union { float f; uint u; } c; c.f = f;
  return (ushort)((c.u + 0x7fffu + ((c.u >> 16) & 1u)) >> 16);
}
__device__ __forceinline__ float wredsum(float v){
  #pragma unroll
  for (int off = 32; off > 0; off >>= 1) v += __shfl_xor(v, off);
  return v;
}
__device__ __forceinline__ void gload16(const void* g, void* l){
  __builtin_amdgcn_global_load_lds((__attribute__((address_space(1))) void*)(void*)g,
                                   (__attribute__((address_space(3))) void*)l, 16, 0, 0);
}

// ---------- transpose f32 [R][C] -> bf16 [C][R] (optionally split hi/lo), per-z slice ----------
template<bool SPLIT>
__global__ __launch_bounds__(256) void transpose_to_bf16(
    const float* __restrict__ src, ushort* __restrict__ dhi, ushort* __restrict__ dlo,
    int R, int C)
{
  __shared__ float tile[32][33];
  size_t zoff = (size_t)blockIdx.z * R * C;
  src += zoff; dhi += zoff; if (SPLIT) dlo += zoff;
  int c0 = blockIdx.x * 32, r0 = blockIdx.y * 32;
  int tx = threadIdx.x & 31, ty = threadIdx.x >> 5;
  #pragma unroll
  for (int i = 0; i < 32; i += 8)
    tile[ty + i][tx] = src[(size_t)(r0 + ty + i) * C + (c0 + tx)];
  __syncthreads();
  #pragma unroll
  for (int i = 0; i < 32; i += 8){
    float v = tile[tx][ty + i];
    ushort hi = f2bf(v);
    dhi[(size_t)(c0 + ty + i) * R + (r0 + tx)] = hi;
    if constexpr (SPLIT)
      dlo[(size_t)(c0 + ty + i) * R + (r0 + tx)] = f2bf(v - bf2f(hi));
  }
}

// ---------- LN1: x[N,512] f32 -> h split bf16 hi/lo ----------
__global__ __launch_bounds__(256) void ln_split(
    const float* __restrict__ x, const float* __restrict__ g, const float* __restrict__ b,
    ushort* __restrict__ hhi, ushort* __restrict__ hlo)
{
  int w = threadIdx.x >> 6, lane = threadIdx.x & 63;
  int row = blockIdx.x * 4 + w;
  const float* xr = x + (size_t)row * 512;
  int d = lane * 8;
  float4 a0 = *(const float4*)(xr + d);
  float4 a1 = *(const float4*)(xr + d + 4);
  float v[8] = {a0.x,a0.y,a0.z,a0.w,a1.x,a1.y,a1.z,a1.w};
  float s = 0.f;
  #pragma unroll
  for (int j = 0; j < 8; j++) s += v[j];
  s = wredsum(s);
  float mean = s * (1.f/512.f);
  float q = 0.f;
  #pragma unroll
  for (int j = 0; j < 8; j++){ float t = v[j] - mean; q += t*t; }
  q = wredsum(q);
  float rstd = rsqrtf(q * (1.f/512.f) + 1e-5f);
  ushort hu[8], lu[8];
  #pragma unroll
  for (int j = 0; j < 8; j++){
    float h = (v[j] - mean) * rstd * g[d+j] + b[d+j];
    ushort hi = f2bf(h);
    hu[j] = hi;
    lu[j] = f2bf(h - bf2f(hi));
  }
  uint4 oh, ol;
  oh.x = (uint)hu[0] | ((uint)hu[1]<<16); oh.y = (uint)hu[2] | ((uint)hu[3]<<16);
  oh.z = (uint)hu[4] | ((uint)hu[5]<<16); oh.w = (uint)hu[6] | ((uint)hu[7]<<16);
  ol.x = (uint)lu[0] | ((uint)lu[1]<<16); ol.y = (uint)lu[2] | ((uint)lu[3]<<16);
  ol.z = (uint)lu[4] | ((uint)lu[5]<<16); ol.w = (uint)lu[6] | ((uint)lu[7]<<16);
  *(uint4*)(hhi + (size_t)row*512 + d) = oh;
  *(uint4*)(hlo + (size_t)row*512 + d) = ol;
}

// ---------- GEMM: C[M,N] = A[M,K] * Bt[N,K]^T, 128x128 tile, BK=32, 4 waves ----------
// EP: 0 = store f32 (qkv)   1 = +bias[col]+resid -> f32 (proj)
//     2 = gelu(acc+bias) -> bf16 (mid)   3 = outF += scale[row*4+e]*(acc+bias) (moe)
template<int EP, bool SPLIT>
__global__ __launch_bounds__(256) void gemm_bt(
    const ushort* __restrict__ A, const ushort* __restrict__ Alo,
    const ushort* __restrict__ B, const ushort* __restrict__ Blo,
    int M, int N, int K,
    ushort* __restrict__ outB, float* __restrict__ outF,
    const float* __restrict__ bias, const float* __restrict__ resid,
    const float* __restrict__ scalev, int expert)
{
  __shared__ __align__(16) ushort As[2][128*32];
  __shared__ __align__(16) ushort Bs[2][128*32];
  const int tid  = threadIdx.x;
  const int lane = tid & 63;
  const int w    = tid >> 6;
  const int wm   = w >> 1, wn = w & 1;
  const int bm   = blockIdx.x, bn = blockIdx.y;

  const int    srow = w*16 + (lane >> 2);
  const int    scol = (lane & 3) * 8;
  const size_t aoff = (size_t)(bm*128 + srow) * K + scol;
  const size_t boff = (size_t)(bn*128 + srow) * K + scol;
  const int lbase0 = (w*16) * 32;
  const int lbase1 = (64 + w*16) * 32;

  f32x4 acc[4][4];
  #pragma unroll
  for (int i = 0; i < 4; i++)
    #pragma unroll
    for (int j = 0; j < 4; j++) acc[i][j] = f32x4{0.f,0.f,0.f,0.f};

  const int nk = K >> 5;
  for (int kt = 0; kt < nk; ++kt) {
    const size_t ko = (size_t)kt * 32;
    gload16(A + aoff + ko,               &As[0][lbase0]);
    gload16(A + aoff + (size_t)64*K + ko,&As[0][lbase1]);
    gload16(B + boff + ko,               &Bs[0][lbase0]);
    gload16(B + boff + (size_t)64*K + ko,&Bs[0][lbase1]);
    if constexpr (SPLIT) {
      gload16(Alo + aoff + ko,               &As[1][lbase0]);
      gload16(Alo + aoff + (size_t)64*K + ko,&As[1][lbase1]);
      gload16(Blo + boff + ko,               &Bs[1][lbase0]);
      gload16(Blo + boff + (size_t)64*K + ko,&Bs[1][lbase1]);
    }
    __syncthreads();

    bf16x8 ah[4], bh[4], al[4], bl[4];
    const int kk = (lane >> 4) * 8;
    const int ar = wm*64 + (lane & 15);
    const int br = wn*64 + (lane & 15);
    #pragma unroll
    for (int i = 0; i < 4; i++){
      ah[i] = *(const bf16x8*)&As[0][(ar + i*16)*32 + kk];
      bh[i] = *(const bf16x8*)&Bs[0][(br + i*16)*32 + kk];
      if constexpr (SPLIT){
        al[i] = *(const bf16x8*)&As[1][(ar + i*16)*32 + kk];
        bl[i] = *(const bf16x8*)&Bs[1][(br + i*16)*32 + kk];
      }
    }
    #pragma unroll
    for (int i = 0; i < 4; i++)
      #pragma unroll
      for (int j = 0; j < 4; j++){
        acc[i][j] = __builtin_amdgcn_mfma_f32_16x16x32_bf16(ah[i], bh[j], acc[i][j], 0,0,0);
        if constexpr (SPLIT){
          acc[i][j] = __builtin_amdgcn_mfma_f32_16x16x32_bf16(ah[i], bl[j], acc[i][j], 0,0,0);
          acc[i][j] = __builtin_amdgcn_mfma_f32_16x16x32_bf16(al[i], bh[j], acc[i][j], 0,0,0);
        }
      }
    __syncthreads();
  }

  const int r0 = bm*128 + wm*64;
  const int c0 = bn*128 + wn*64;
  const int cl = lane & 15;
  const int rl = (lane >> 4) * 4;
  #pragma unroll
  for (int i = 0; i < 4; i++){
    #pragma unroll
    for (int j = 0; j < 4; j++){
      #pragma unroll
      for (int r = 0; r < 4; r++){
        int row = r0 + i*16 + rl + r;
        int col = c0 + j*16 + cl;
        float v = acc[i][j][r];
        size_t idx = (size_t)row * N + col;
        if constexpr (EP == 0) {
          outF[idx] = v;
        } else if constexpr (EP == 1) {
          outF[idx] = v + bias[col] + resid[idx];
        } else if constexpr (EP == 2) {
          float t = v + bias[col];
          float u = 0.7978845608028654f * (t + 0.044715f * t*t*t);
          outB[idx] = f2bf(0.5f * t * (1.0f + tanhf(u)));
        } else {
          float sc = scalev[(size_t)row*4 + expert];
          outF[idx] += sc * (v + bias[col]);
        }
      }
    }
  }
}

// ---------- attention: one wave per (b,h); qkv f32 [N,1536]; out att split bf16 [N,512] ----------
__global__ __launch_bounds__(64) void attn32(
    const float* __restrict__ qkv, ushort* __restrict__ atthi, ushort* __restrict__ attlo)
{
  int bh = blockIdx.x; int b = bh >> 4, h = bh & 15;
  __shared__ float qs[32][33], ks[32][33], vs[32][33], ps[32][33];
  int lane = threadIdx.x;
  int t = lane >> 1, cb = (lane & 1) * 16;
  const float* src = qkv + (size_t)(b*32 + t)*1536 + h*32 + cb;
  #pragma unroll
  for (int j = 0; j < 16; j += 4){
    float4 q4 = *(const float4*)(src + j);
    float4 k4 = *(const float4*)(src + 512 + j);
    float4 v4 = *(const float4*)(src + 1024 + j);
    qs[t][cb+j]=q4.x; qs[t][cb+j+1]=q4.y; qs[t][cb+j+2]=q4.z; qs[t][cb+j+3]=q4.w;
    ks[t][cb+j]=k4.x; ks[t][cb+j+1]=k4.y; ks[t][cb+j+2]=k4.z; ks[t][cb+j+3]=k4.w;
    vs[t][cb+j]=v4.x; vs[t][cb+j+1]=v4.y; vs[t][cb+j+2]=v4.z; vs[t][cb+j+3]=v4.w;
  }
  __syncthreads();
  const float scale = 0.044194173824159216f; // 1/sqrt(512)
  float sc[16];
  #pragma unroll
  for (int j = 0; j < 16; j++){
    int c = cb + j;
    if (c <= t) {
      float d = 0.f;
      #pragma unroll
      for (int i = 0; i < 32; i++) d += qs[t][i] * ks[c][i];
      sc[j] = d * scale;
    } else sc[j] = -1e30f;
  }
  float mx = -1e30f;
  #pragma unroll
  for (int j = 0; j < 16; j++) mx = fmaxf(mx, sc[j]);
  mx = fmaxf(mx, __shfl_xor(mx, 1));
  float p[16], sum = 0.f;
  #pragma unroll
  for (int j = 0; j < 16; j++){
    int c = cb + j;
    if (c <= t) { p[j] = expf(sc[j] - mx); sum += p[j]; } else p[j] = 0.f;
  }
  sum += __shfl_xor(sum, 1);
  float inv = 1.f / sum;
  #pragma unroll
  for (int j = 0; j < 16; j++) ps[t][cb+j] = p[j] * inv;
  __syncthreads();
  float o[16];
  #pragma unroll
  for (int j = 0; j < 16; j++) o[j] = 0.f;
  for (int s2 = 0; s2 <= t; ++s2){
    float wv = ps[t][s2];
    #pragma unroll
    for (int j = 0; j < 16; j++) o[j] += wv * vs[s2][cb+j];
  }
  size_t base = (size_t)(b*32 + t)*512 + h*32 + cb;
  ushort hu[16], lu[16];
  #pragma unroll
  for (int j = 0; j < 16; j++){
    ushort hi = f2bf(o[j]);
    hu[j] = hi; lu[j] = f2bf(o[j] - bf2f(hi));
  }
  uint4 oh0, oh1, ol0, ol1;
  oh0.x=(uint)hu[0]|((uint)hu[1]<<16);  oh0.y=(uint)hu[2]|((uint)hu[3]<<16);
  oh0.z=(uint)hu[4]|((uint)hu[5]<<16);  oh0.w=(uint)hu[6]|((uint)hu[7]<<16);
  oh1.x=(uint)hu[8]|((uint)hu[9]<<16);  oh1.y=(uint)hu[10]|((uint)hu[11]<<16);
  oh1.z=(uint)hu[12]|((uint)hu[13]<<16);oh1.w=(uint)hu[14]|((uint)hu[15]<<16);
  ol0.x=(uint)lu[0]|((uint)lu[1]<<16);  ol0.y=(uint)lu[2]|((uint)lu[3]<<16);
  ol0.z=(uint)lu[4]|((uint)lu[5]<<16);  ol0.w=(uint)lu[6]|((uint)lu[7]<<16);
  ol1.x=(uint)lu[8]|((uint)lu[9]<<16);  ol1.y=(uint)lu[10]|((uint)lu[11]<<16);
  ol1.z=(uint)lu[12]|((uint)lu[13]<<16);ol1.w=(uint)lu[14]|((uint)lu[15]<<16);
  *(uint4*)(atthi + base)     = oh0;  *(uint4*)(atthi + base + 8) = oh1;
  *(uint4*)(attlo + base)     = ol0;  *(uint4*)(attlo + base + 8) = ol1;
}

// ---------- LN2 + gate: x1 f32 -> h2 bf16, combine [N,4] f32, per-block logit partials ----------
__global__ __launch_bounds__(256) void ln2_gate(
    const float* __restrict__ x1, const float* __restrict__ g, const float* __restrict__ b,
    const float* __restrict__ wgate, ushort* __restrict__ h2,
    float* __restrict__ combine, float* __restrict__ partials)
{
  __shared__ float wsumLds[4];
  int w = threadIdx.x >> 6, lane = threadIdx.x & 63;
  int row = blockIdx.x * 4 + w;
  const float* xr = x1 + (size_t)row * 512;
  int d = lane * 8;
  float4 a0 = *(const float4*)(xr + d);
  float4 a1 = *(const float4*)(xr + d + 4);
  float v[8] = {a0.x,a0.y,a0.z,a0.w,a1.x,a1.y,a1.z,a1.w};
  float s = 0.f;
  #pragma unroll
  for (int j = 0; j < 8; j++) s += v[j];
  s = wredsum(s);
  float mean = s * (1.f/512.f);
  float q = 0.f;
  #pragma unroll
  for (int j = 0; j < 8; j++){ float t = v[j] - mean; q += t*t; }
  q = wredsum(q);
  float rstd = rsqrtf(q * (1.f/512.f) + 1e-5f);
  float acc0=0.f, acc1=0.f, acc2=0.f, acc3=0.f;
  ushort hu[8];
  #pragma unroll
  for (int j = 0; j < 8; j++){
    float h = (v[j] - mean) * rstd * g[d+j] + b[d+j];
    hu[j] = f2bf(h);
    float4 wgv = *(const float4*)(wgate + (size_t)(d+j)*4);
    acc0 += h * wgv.x; acc1 += h * wgv.y; acc2 += h * wgv.z; acc3 += h * wgv.w;
  }
  uint4 oh;
  oh.x=(uint)hu[0]|((uint)hu[1]<<16); oh.y=(uint)hu[2]|((uint)hu[3]<<16);
  oh.z=(uint)hu[4]|((uint)hu[5]<<16); oh.w=(uint)hu[6]|((uint)hu[7]<<16);
  *(uint4*)(h2 + (size_t)row*512 + d) = oh;
  acc0 = wredsum(acc0); acc1 = wredsum(acc1); acc2 = wredsum(acc2); acc3 = wredsum(acc3);
  if (lane == 0){
    float l[4] = {acc0, acc1, acc2, acc3};
    int i0 = 0;
    for (int e = 1; e < 4; e++) if (l[e] > l[i0]) i0 = e;
    int i1 = -1;
    for (int e = 0; e < 4; e++){ if (e == i0) continue; if (i1 < 0 || l[e] > l[i1]) i1 = e; }
    float e1 = expf(l[i1] - l[i0]);
    float w1v = e1 / (1.f + e1), w0v = 1.f / (1.f + e1);
    float carr[4] = {0.f,0.f,0.f,0.f};
    carr[i0] = w0v; carr[i1] = w1v;
    float* cp = combine + (size_t)row*4;
    cp[0]=carr[0]; cp[1]=carr[1]; cp[2]=carr[2]; cp[3]=carr[3];
    wsumLds[w] = l[0] + l[1] + l[2] + l[3];
  }
  __syncthreads();
  if (threadIdx.x == 0)
    partials[blockIdx.x] = wsumLds[0] + wsumLds[1] + wsumLds[2] + wsumLds[3];
}

__global__ __launch_bounds__(256) void gate_reduce(
    const float* __restrict__ partials, int n, float* __restrict__ out)
{
  __shared__ float ws4[4];
  float s = 0.f;
  for (int i = threadIdx.x; i < n; i += 256) s += partials[i];
  s = wredsum(s);
  if ((threadIdx.x & 63) == 0) ws4[threadIdx.x >> 6] = s;
  __syncthreads();
  if (threadIdx.x == 0){
    float tot = ws4[0] + ws4[1] + ws4[2] + ws4[3];
    float ep = tot * (1.f/65536.f);
    out[0] = ep * logf(ep + 0.1f);
  }
}

// ---------- host ----------
extern "C" void kernel_launch(void* const* d_in, const int* in_sizes, int n_in,
                              void* d_out, int out_size, void* d_ws, size_t ws_size,
                              hipStream_t stream)
{
  const float* x     = (const float*)d_in[0];
  const float* ln1g  = (const float*)d_in[1];
  const float* ln1b  = (const float*)d_in[2];
  const float* wq    = (const float*)d_in[3];
  const float* wk    = (const float*)d_in[4];
  const float* wv    = (const float*)d_in[5];
  const float* wproj = (const float*)d_in[6];
  const float* bproj = (const float*)d_in[7];
  const float* ln2g  = (const float*)d_in[8];
  const float* ln2b  = (const float*)d_in[9];
  const float* wgate = (const float*)d_in[10];
  const float* w1    = (const float*)d_in[11];
  const float* b1    = (const float*)d_in[12];
  const float* w2    = (const float*)d_in[13];
  const float* b2    = (const float*)d_in[14];
  float* out = (float*)d_out;

  char* ws = (char*)d_ws;
  ushort* hHi   = (ushort*)(ws + 0);
  ushort* hLo   = (ushort*)(ws + 16777216);
  ushort* qkvTh = (ushort*)(ws + 33554432);
  ushort* qkvTl = (ushort*)(ws + 35127296);
  ushort* pTh   = (ushort*)(ws + 36700160);
  ushort* pTl   = (ushort*)(ws + 37224448);
  ushort* w1T   = (ushort*)(ws + 37748736);
  ushort* w2T   = (ushort*)(ws + 46137344);
  float*  combine  = (float*)(ws + 54525952);
  float*  partials = (float*)(ws + 54788096);
  ushort* h2    = (ushort*)(ws + 54804480);
  ushort* attHi = (ushort*)(ws + 71581696);
  ushort* attLo = (ushort*)(ws + 88358912);
  float*  qkvF  = (float*)(ws + 105136128);
  ushort* mid   = (ushort*)(ws + 105136128); // reuses qkvF region (dead after attention)

  // weight prep (transpose + bf16 [split] conversion)
  transpose_to_bf16<true ><<<dim3(1,16,16), 256, 0, stream>>>(wq,    qkvTh,          qkvTl,          512, 32);
  transpose_to_bf16<true ><<<dim3(1,16,16), 256, 0, stream>>>(wk,    qkvTh + 262144, qkvTl + 262144, 512, 32);
  transpose_to_bf16<true ><<<dim3(1,16,16), 256, 0, stream>>>(wv,    qkvTh + 524288, qkvTl + 524288, 512, 32);
  transpose_to_bf16<true ><<<dim3(16,16,1), 256, 0, stream>>>(wproj, pTh,            pTl,            512, 512);
  transpose_to_bf16<false><<<dim3(64,16,4), 256, 0, stream>>>(w1,    w1T,            nullptr,        512, 2048);
  transpose_to_bf16<false><<<dim3(16,64,4), 256, 0, stream>>>(w2,    w2T,            nullptr,        2048, 512);

  // LN1 (split precision)
  ln_split<<<dim3(4096), 256, 0, stream>>>(x, ln1g, ln1b, hHi, hLo);

  // QKV = h @ Wqkv (split-bf16, f32-grade) -> f32 [N,1536]
  gemm_bt<0,true><<<dim3(128,12), 256, 0, stream>>>(hHi, hLo, qkvTh, qkvTl,
      16384, 1536, 512, nullptr, qkvF, nullptr, nullptr, nullptr, 0);

  // attention per (b,h)
  attn32<<<dim3(8192), 64, 0, stream>>>(qkvF, attHi, attLo);

  // x1 = x + att @ Wproj + b_proj (split-bf16) -> d_out f32
  gemm_bt<1,true><<<dim3(128,4), 256, 0, stream>>>(attHi, attLo, pTh, pTl,
      16384, 512, 512, nullptr, out, bproj, x, nullptr, 0);

  // LN2 + gate (f32 logits, top-2 softmax -> combine), balance-loss partials
  ln2_gate<<<dim3(4096), 256, 0, stream>>>(out, ln2g, ln2b, wgate, h2, combine, partials);
  gate_reduce<<<dim3(1), 256, 0, stream>>>(partials, 4096, out + 8388608);

  // MoE (dense over 4 experts, bf16 MFMA)
  for (int e = 0; e < 4; e++){
    gemm_bt<2,false><<<dim3(128,16), 256, 0, stream>>>(h2, nullptr, w1T + (size_t)e*1048576, nullptr,
        16384, 2048, 512, mid, nullptr, b1 + e*2048, nullptr, nullptr, 0);
    gemm_bt<3,false><<<dim3(128,4), 256, 0, stream>>>(mid, nullptr, w2T + (size_t)e*1048576, nullptr,
        16384, 512, 2048, nullptr, out, b2 + e*512, nullptr, combine, e);
  }
}